// Round 6
// baseline (1755.039 us; speedup 1.0000x reference)
//
#include <hip/hip_runtime.h>
#include <cstdint>
#include <cstddef>

#define N_VARS   4000
#define N_LITS   8000
#define MP_L     8064     // N_LITS padded to 128-row tiles
#define N_CLAUSES 16000
#define N_CELLS  48000
#define DIM      128
#define N_ROUNDS 16
#define N_PROBS  8

typedef __bf16 bf16x8 __attribute__((ext_vector_type(8)));
typedef float f32x4 __attribute__((ext_vector_type(4)));

__device__ inline unsigned short f2bf(float x) {
  unsigned int u = __float_as_uint(x);
  u += 0x7fffu + ((u >> 16) & 1u);          // RTNE
  return (unsigned short)(u >> 16);
}
__device__ inline float bflo(unsigned int v) { return __uint_as_float(v << 16); }
__device__ inline float bfhi(unsigned int v) { return __uint_as_float(v & 0xffff0000u); }
__device__ inline unsigned int pack2(float a, float b) {
  return (unsigned int)f2bf(a) | ((unsigned int)f2bf(b) << 16);
}
__device__ inline bf16x8 ld_frag(const unsigned short* p) {
  uint4 u = *reinterpret_cast<const uint4*>(p);
  return __builtin_bit_cast(bf16x8, u);
}
__device__ inline float fast_sigmoid(float x) { return 1.f / (1.f + __expf(-x)); }
__device__ inline float fast_tanh(float x) {
  float t = __expf(-2.f * x);
  return (1.f - t) / (1.f + t);
}

// ===========================================================================
// gemm_lstm<KTILES>: gates[M,512] = X[M,K] @ Wp[512,K]^T + bP, fused LSTM.
// 128x128 tile, 256 thr = 4 waves (2x2), 4x4 16x16 MFMA micro-tiles.
// Both operands LDS-staged (padded rows, 2-way-free conflicts).
// Wp rows gate-permuted: np = bx*128 + wn*64 + ni*16 + kc*4 + j
//   <-> orig row = j*128 + d,  d = bx*32 + wn*16 + ni*4 + kc
// so lane (r,kc), tile (mi,ni) holds i,f,g,o of (row=m0+wm*64+mi*16+r, dim d)
// in acc[mi][ni][0..3]. Zero-shuffle LSTM; c fp32 rmw, h bf16 out.
// ===========================================================================
template<int KTILES>
__global__ __launch_bounds__(256) void gemm_lstm(
    const unsigned short* __restrict__ X,
    const unsigned short* __restrict__ Wp,
    const float* __restrict__ bP,
    float* __restrict__ cst, unsigned short* __restrict__ hnew) {
  constexpr int K = KTILES * 64;
  __shared__ __align__(16) unsigned short Xs[128][72];
  __shared__ __align__(16) unsigned short Ws[128][72];
  const int tid = threadIdx.x;
  const int w = tid >> 6, l = tid & 63;
  const int r = l & 15, kc = l >> 4;
  const int wm = w >> 1, wn = w & 1;
  const int m0 = blockIdx.y * 128, n0 = blockIdx.x * 128;

  f32x4 acc[4][4];
#pragma unroll
  for (int mi = 0; mi < 4; ++mi)
#pragma unroll
    for (int ni = 0; ni < 4; ++ni) acc[mi][ni] = (f32x4){0.f, 0.f, 0.f, 0.f};

  for (int kt = 0; kt < KTILES; ++kt) {
    if (kt) __syncthreads();
#pragma unroll
    for (int q = 0; q < 4; ++q) {
      const int cidx = tid + q * 256;
      const int row = cidx >> 3, ck = cidx & 7;
      *reinterpret_cast<uint4*>(&Xs[row][ck * 8]) =
          *reinterpret_cast<const uint4*>(&X[(size_t)(m0 + row) * K + kt * 64 + ck * 8]);
      *reinterpret_cast<uint4*>(&Ws[row][ck * 8]) =
          *reinterpret_cast<const uint4*>(&Wp[(size_t)(n0 + row) * K + kt * 64 + ck * 8]);
    }
    __syncthreads();
#pragma unroll
    for (int ks = 0; ks < 2; ++ks) {
      bf16x8 xf[4], wf[4];
#pragma unroll
      for (int mi = 0; mi < 4; ++mi) xf[mi] = ld_frag(&Xs[wm * 64 + mi * 16 + r][ks * 32 + kc * 8]);
#pragma unroll
      for (int ni = 0; ni < 4; ++ni) wf[ni] = ld_frag(&Ws[wn * 64 + ni * 16 + r][ks * 32 + kc * 8]);
#pragma unroll
      for (int mi = 0; mi < 4; ++mi)
#pragma unroll
        for (int ni = 0; ni < 4; ++ni)
          acc[mi][ni] = __builtin_amdgcn_mfma_f32_16x16x32_bf16(wf[ni], xf[mi], acc[mi][ni], 0, 0, 0);
    }
  }

#pragma unroll
  for (int ni = 0; ni < 4; ++ni) {
    const float4 bb = *reinterpret_cast<const float4*>(&bP[n0 + wn * 64 + ni * 16 + kc * 4]);
    const int d = blockIdx.x * 32 + wn * 16 + ni * 4 + kc;
#pragma unroll
    for (int mi = 0; mi < 4; ++mi) {
      const int row = m0 + wm * 64 + mi * 16 + r;
      const size_t idx = (size_t)row * 128 + d;
      const float ig = acc[mi][ni][0] + bb.x;
      const float fg = acc[mi][ni][1] + bb.y;
      const float gg = acc[mi][ni][2] + bb.z;
      const float og = acc[mi][ni][3] + bb.w;
      const float cp = cst[idx];
      const float cn = fast_sigmoid(fg) * cp + fast_sigmoid(ig) * fast_tanh(gg);
      cst[idx] = cn;
      hnew[idx] = f2bf(fast_sigmoid(og) * fast_tanh(cn));
    }
  }
}

// ---------------------------------------------------------------------------
// Gathers (wave-per-row, pure latency kernels, large grids).
// ---------------------------------------------------------------------------
__global__ void gather_cls(const int* __restrict__ ptr, const int* __restrict__ col,
                           const unsigned short* __restrict__ Lpre,
                           const unsigned short* __restrict__ Ch,
                           unsigned short* __restrict__ X) {
  const int row = blockIdx.x * 4 + (threadIdx.x >> 6);
  const int l = threadIdx.x & 63;
  const int b = ptr[row], e = ptr[row + 1];
  float s0 = 0.f, s1 = 0.f;
  for (int j = b; j < e; ++j) {
    unsigned int v = *reinterpret_cast<const unsigned int*>(&Lpre[(size_t)col[j] * 128 + 2 * l]);
    s0 += bflo(v); s1 += bfhi(v);
  }
  unsigned int* Xo = reinterpret_cast<unsigned int*>(&X[(size_t)row * 256]);
  Xo[l] = pack2(s0, s1);
  Xo[64 + l] = *reinterpret_cast<const unsigned int*>(&Ch[(size_t)row * 128 + 2 * l]);
}

__global__ void gather_lit(const int* __restrict__ ptr, const int* __restrict__ col,
                           const unsigned short* __restrict__ Cpre,
                           const unsigned short* __restrict__ Lh,
                           unsigned short* __restrict__ X) {
  const int row = blockIdx.x * 4 + (threadIdx.x >> 6);
  const int l = threadIdx.x & 63;
  unsigned int* Xo = reinterpret_cast<unsigned int*>(&X[(size_t)row * 384]);
  if (row >= N_LITS) {   // pad rows -> zeros (harmless garbage downstream)
    Xo[l] = 0; Xo[64 + l] = 0; Xo[128 + l] = 0;
    return;
  }
  const int b = ptr[row], e = ptr[row + 1];
  float s0 = 0.f, s1 = 0.f;
  for (int j = b; j < e; ++j) {
    unsigned int v = *reinterpret_cast<const unsigned int*>(&Cpre[(size_t)col[j] * 128 + 2 * l]);
    s0 += bflo(v); s1 += bfhi(v);
  }
  const int flip = (row < N_VARS) ? row + N_VARS : row - N_VARS;
  Xo[l] = pack2(s0, s1);
  Xo[64 + l] = *reinterpret_cast<const unsigned int*>(&Lh[(size_t)flip * 128 + 2 * l]);
  Xo[128 + l] = *reinterpret_cast<const unsigned int*>(&Lh[(size_t)row * 128 + 2 * l]);
}

// ---------------------------------------------------------------------------
// Fused 3-layer MLP: 256 thr = 4 waves, 64 rows/block, wave-private (no barriers).
// ---------------------------------------------------------------------------
__global__ __launch_bounds__(256) void fused_mlp3(
    const unsigned short* __restrict__ A,
    const unsigned short* __restrict__ W1, const float* __restrict__ b1,
    const unsigned short* __restrict__ W2, const float* __restrict__ b2,
    const unsigned short* __restrict__ W3, const float* __restrict__ b3,
    unsigned short* __restrict__ out) {
  __shared__ __align__(16) unsigned short xbuf[2][4][16][136];
  const int w = threadIdx.x >> 6, l = threadIdx.x & 63;
  const int r = l & 15, kc = l >> 4;
  const int row0 = blockIdx.x * 64 + w * 16;

  f32x4 acc[8];
#pragma unroll
  for (int t = 0; t < 8; ++t) acc[t] = (f32x4){0.f, 0.f, 0.f, 0.f};
#pragma unroll
  for (int ks = 0; ks < 4; ++ks) {
    bf16x8 a = ld_frag(&A[(size_t)(row0 + r) * 128 + ks * 32 + kc * 8]);
#pragma unroll
    for (int t = 0; t < 8; ++t) {
      bf16x8 b = ld_frag(&W1[(size_t)(t * 16 + r) * 128 + ks * 32 + kc * 8]);
      acc[t] = __builtin_amdgcn_mfma_f32_16x16x32_bf16(a, b, acc[t], 0, 0, 0);
    }
  }
#pragma unroll
  for (int t = 0; t < 8; ++t) {
    float bv = b1[t * 16 + r];
#pragma unroll
    for (int j = 0; j < 4; ++j)
      xbuf[0][w][kc * 4 + j][t * 16 + r] = f2bf(fmaxf(acc[t][j] + bv, 0.f));
  }
#pragma unroll
  for (int t = 0; t < 8; ++t) acc[t] = (f32x4){0.f, 0.f, 0.f, 0.f};
#pragma unroll
  for (int ks = 0; ks < 4; ++ks) {
    bf16x8 a = ld_frag(&xbuf[0][w][r][ks * 32 + kc * 8]);
#pragma unroll
    for (int t = 0; t < 8; ++t) {
      bf16x8 b = ld_frag(&W2[(size_t)(t * 16 + r) * 128 + ks * 32 + kc * 8]);
      acc[t] = __builtin_amdgcn_mfma_f32_16x16x32_bf16(a, b, acc[t], 0, 0, 0);
    }
  }
#pragma unroll
  for (int t = 0; t < 8; ++t) {
    float bv = b2[t * 16 + r];
#pragma unroll
    for (int j = 0; j < 4; ++j)
      xbuf[1][w][kc * 4 + j][t * 16 + r] = f2bf(fmaxf(acc[t][j] + bv, 0.f));
  }
#pragma unroll
  for (int t = 0; t < 8; ++t) acc[t] = (f32x4){0.f, 0.f, 0.f, 0.f};
#pragma unroll
  for (int ks = 0; ks < 4; ++ks) {
    bf16x8 a = ld_frag(&xbuf[1][w][r][ks * 32 + kc * 8]);
#pragma unroll
    for (int t = 0; t < 8; ++t) {
      bf16x8 b = ld_frag(&W3[(size_t)(t * 16 + r) * 128 + ks * 32 + kc * 8]);
      acc[t] = __builtin_amdgcn_mfma_f32_16x16x32_bf16(a, b, acc[t], 0, 0, 0);
    }
  }
#pragma unroll
  for (int t = 0; t < 8; ++t) {
    float bv = b3[t * 16 + r];
#pragma unroll
    for (int j = 0; j < 4; ++j)
      out[(size_t)(row0 + kc * 4 + j) * 128 + t * 16 + r] = f2bf(acc[t][j] + bv);
  }
}

// ---------------------------------------------------------------------------
// Fused vote: relu(relu(A@W1^T+b1)@W2^T+b2) . w3 + b3 -> vote[M] (fp32)
// ---------------------------------------------------------------------------
__global__ __launch_bounds__(256) void fused_vote(
    const unsigned short* __restrict__ A,
    const unsigned short* __restrict__ W1, const float* __restrict__ b1,
    const unsigned short* __restrict__ W2, const float* __restrict__ b2,
    const float* __restrict__ w3, const float* __restrict__ b3,
    float* __restrict__ vote) {
  __shared__ __align__(16) unsigned short xbuf[4][16][136];
  const int w = threadIdx.x >> 6, l = threadIdx.x & 63;
  const int r = l & 15, kc = l >> 4;
  const int row0 = blockIdx.x * 64 + w * 16;

  f32x4 acc[8];
#pragma unroll
  for (int t = 0; t < 8; ++t) acc[t] = (f32x4){0.f, 0.f, 0.f, 0.f};
#pragma unroll
  for (int ks = 0; ks < 4; ++ks) {
    bf16x8 a = ld_frag(&A[(size_t)(row0 + r) * 128 + ks * 32 + kc * 8]);
#pragma unroll
    for (int t = 0; t < 8; ++t) {
      bf16x8 b = ld_frag(&W1[(size_t)(t * 16 + r) * 128 + ks * 32 + kc * 8]);
      acc[t] = __builtin_amdgcn_mfma_f32_16x16x32_bf16(a, b, acc[t], 0, 0, 0);
    }
  }
#pragma unroll
  for (int t = 0; t < 8; ++t) {
    float bv = b1[t * 16 + r];
#pragma unroll
    for (int j = 0; j < 4; ++j)
      xbuf[w][kc * 4 + j][t * 16 + r] = f2bf(fmaxf(acc[t][j] + bv, 0.f));
  }
#pragma unroll
  for (int t = 0; t < 8; ++t) acc[t] = (f32x4){0.f, 0.f, 0.f, 0.f};
#pragma unroll
  for (int ks = 0; ks < 4; ++ks) {
    bf16x8 a = ld_frag(&xbuf[w][r][ks * 32 + kc * 8]);
#pragma unroll
    for (int t = 0; t < 8; ++t) {
      bf16x8 b = ld_frag(&W2[(size_t)(t * 16 + r) * 128 + ks * 32 + kc * 8]);
      acc[t] = __builtin_amdgcn_mfma_f32_16x16x32_bf16(a, b, acc[t], 0, 0, 0);
    }
  }
  float vs[4] = {0.f, 0.f, 0.f, 0.f};
#pragma unroll
  for (int t = 0; t < 8; ++t) {
    float bv = b2[t * 16 + r], wv = w3[t * 16 + r];
#pragma unroll
    for (int j = 0; j < 4; ++j)
      vs[j] += fmaxf(acc[t][j] + bv, 0.f) * wv;
  }
#pragma unroll
  for (int off = 1; off < 16; off <<= 1) {
#pragma unroll
    for (int j = 0; j < 4; ++j) vs[j] += __shfl_xor(vs[j], off, 16);
  }
  if (r == 0) {
#pragma unroll
    for (int j = 0; j < 4; ++j) vote[row0 + kc * 4 + j] = vs[j] + b3[0];
  }
}

// ---------------------------------------------------------------------------
// One-time prep.
// ---------------------------------------------------------------------------
__global__ void init_state_kernel(const float* __restrict__ Lw, const float* __restrict__ Lb,
                                  const float* __restrict__ Cw, const float* __restrict__ Cb,
                                  unsigned short* __restrict__ Lh, float* __restrict__ Lc,
                                  unsigned short* __restrict__ Ch, float* __restrict__ Cc) {
  int idx = blockIdx.x * 256 + threadIdx.x;
  if (idx >= N_CLAUSES * DIM) return;
  int d = idx & 127;
  Ch[idx] = f2bf(Cw[d] + Cb[d]);
  Cc[idx] = 0.f;
  if (idx < MP_L * DIM) {          // includes pad rows (never consumed)
    Lh[idx] = f2bf(Lw[d] + Lb[d]);
    Lc[idx] = 0.f;
  }
}

__global__ void cvt8_kernel(const float* s0, const float* s1, const float* s2, const float* s3,
                            const float* s4, const float* s5, const float* s6, const float* s7,
                            unsigned short* d0, unsigned short* d1, unsigned short* d2,
                            unsigned short* d3, unsigned short* d4, unsigned short* d5,
                            unsigned short* d6, unsigned short* d7) {
  int i = blockIdx.x * 256 + threadIdx.x;
  const float* s; unsigned short* d;
  switch (blockIdx.y) {
    case 0: s = s0; d = d0; break;
    case 1: s = s1; d = d1; break;
    case 2: s = s2; d = d2; break;
    case 3: s = s3; d = d3; break;
    case 4: s = s4; d = d4; break;
    case 5: s = s5; d = d5; break;
    case 6: s = s6; d = d6; break;
    default: s = s7; d = d7; break;
  }
  d[i] = f2bf(s[i]);
}

// Gate-permuted W pack for the 128x128-tile gemm_lstm (see its comment).
// np -> orig row: gate = np&3, d = (np>>7)*32 + ((np>>6)&1)*16 + ((np>>4)&3)*4 + ((np>>2)&3).
template<int KIH>
__global__ void pack_gates_kernel(const float* __restrict__ wih, const float* __restrict__ whh,
                                  const float* __restrict__ bih, const float* __restrict__ bhh,
                                  unsigned short* __restrict__ Wp, float* __restrict__ bP) {
  constexpr int K = KIH + 128;
  int idx = blockIdx.x * 256 + threadIdx.x;
  if (idx >= 512 * K) return;
  int np = idx / K, k = idx % K;
  int gt = np & 3;
  int d = ((np >> 7) << 5) + (((np >> 6) & 1) << 4) + (((np >> 4) & 3) << 2) + ((np >> 2) & 3);
  int orig = gt * 128 + d;
  float v = (k < KIH) ? wih[(size_t)orig * KIH + k] : whh[(size_t)orig * 128 + (k - KIH)];
  Wp[idx] = f2bf(v);
  if (k == 0) bP[np] = bih[orig] + bhh[orig];
}

// ---------------------------------------------------------------------------
// CSR build.
// ---------------------------------------------------------------------------
__global__ void count_kernel(const int* __restrict__ uidx,
                             int* __restrict__ lit_cnt, int* __restrict__ cls_cnt) {
  int i = blockIdx.x * 256 + threadIdx.x;
  if (i < N_CELLS) {
    atomicAdd(&lit_cnt[uidx[2 * i]], 1);
    atomicAdd(&cls_cnt[uidx[2 * i + 1]], 1);
  }
}

__global__ void scan_kernel(const int* __restrict__ cnt, int* __restrict__ ptr, int n) {
  __shared__ int part[1024];
  __shared__ int total;
  int t = threadIdx.x;
  int chunk = (n + 1023) >> 10;
  int lo = t * chunk, hi = min(lo + chunk, n);
  int s = 0;
  for (int i = lo; i < hi; ++i) s += cnt[i];
  part[t] = s;
  __syncthreads();
  if (t == 0) {
    int acc = 0;
    for (int i = 0; i < 1024; ++i) { int v = part[i]; part[i] = acc; acc += v; }
    total = acc;
  }
  __syncthreads();
  int acc = part[t];
  for (int i = lo; i < hi; ++i) { ptr[i] = acc; acc += cnt[i]; }
  if (t == 0) ptr[n] = total;
}

__global__ void scatter_kernel(const int* __restrict__ uidx,
                               const int* __restrict__ lit_ptr, const int* __restrict__ cls_ptr,
                               int* __restrict__ lit_fill, int* __restrict__ cls_fill,
                               int* __restrict__ lit_col, int* __restrict__ cls_col) {
  int i = blockIdx.x * 256 + threadIdx.x;
  if (i < N_CELLS) {
    int lit = uidx[2 * i], cls = uidx[2 * i + 1];
    int p = atomicAdd(&lit_fill[lit], 1);
    lit_col[lit_ptr[lit] + p] = cls;
    int q = atomicAdd(&cls_fill[cls], 1);
    cls_col[cls_ptr[cls] + q] = lit;
  }
}

__global__ void prob_mean_kernel(const float* __restrict__ vote, float* __restrict__ out) {
  int p = blockIdx.x;
  int t = threadIdx.x;
  float s = 0.f;
  for (int i = t; i < 500; i += 256) s += vote[p * 500 + i] + vote[N_VARS + p * 500 + i];
  __shared__ float red[256];
  red[t] = s;
  __syncthreads();
  for (int off = 128; off > 0; off >>= 1) {
    if (t < off) red[t] += red[t + off];
    __syncthreads();
  }
  if (t == 0) out[p] = red[0] * (1.0f / 1000.0f);
}

// ---------------------------------------------------------------------------
extern "C" void kernel_launch(void* const* d_in, const int* in_sizes, int n_in,
                              void* d_out, int out_size, void* d_ws, size_t ws_size,
                              hipStream_t stream) {
  (void)in_sizes; (void)n_in; (void)out_size;
  const int* uidx = (const int*)d_in[0];
  const float* L_init_w = (const float*)d_in[4];
  const float* L_init_b = (const float*)d_in[5];
  const float* C_init_w = (const float*)d_in[6];
  const float* C_init_b = (const float*)d_in[7];
  const float* Lmsg_w1 = (const float*)d_in[8],  *Lmsg_b1 = (const float*)d_in[9];
  const float* Lmsg_w2 = (const float*)d_in[10], *Lmsg_b2 = (const float*)d_in[11];
  const float* Lmsg_w3 = (const float*)d_in[12], *Lmsg_b3 = (const float*)d_in[13];
  const float* Cmsg_w1 = (const float*)d_in[14], *Cmsg_b1 = (const float*)d_in[15];
  const float* Cmsg_w2 = (const float*)d_in[16], *Cmsg_b2 = (const float*)d_in[17];
  const float* Cmsg_w3 = (const float*)d_in[18], *Cmsg_b3 = (const float*)d_in[19];
  const float* Lvote_w1 = (const float*)d_in[20], *Lvote_b1 = (const float*)d_in[21];
  const float* Lvote_w2 = (const float*)d_in[22], *Lvote_b2 = (const float*)d_in[23];
  const float* Lvote_w3 = (const float*)d_in[24], *Lvote_b3 = (const float*)d_in[25];
  const float* Lu_wih = (const float*)d_in[26], *Lu_whh = (const float*)d_in[27];
  const float* Lu_bih = (const float*)d_in[28], *Lu_bhh = (const float*)d_in[29];
  const float* Cu_wih = (const float*)d_in[30], *Cu_whh = (const float*)d_in[31];
  const float* Cu_bih = (const float*)d_in[32], *Cu_bhh = (const float*)d_in[33];
  float* out = (float*)d_out;

  // ---- workspace carve-up ----
  char* base = (char*)d_ws;
  size_t off = 0;
  auto alloc = [&](size_t bytes) {
    void* p = base + off;
    off = (off + bytes + 255) & ~(size_t)255;
    return p;
  };
  float* Lc   = (float*)alloc((size_t)MP_L * DIM * 4);
  float* Cc   = (float*)alloc((size_t)N_CLAUSES * DIM * 4);
  float* bL   = (float*)alloc(512 * 4);
  float* bC   = (float*)alloc(512 * 4);
  float* vote = (float*)alloc(N_LITS * 4);
  unsigned short* Lh  = (unsigned short*)alloc((size_t)MP_L * DIM * 2);
  unsigned short* Ch  = (unsigned short*)alloc((size_t)N_CLAUSES * DIM * 2);
  unsigned short* TL  = (unsigned short*)alloc((size_t)N_LITS * DIM * 2);
  unsigned short* TC  = (unsigned short*)alloc((size_t)N_CLAUSES * DIM * 2);
  unsigned short* XC  = (unsigned short*)alloc((size_t)N_CLAUSES * 256 * 2);
  unsigned short* XL  = (unsigned short*)alloc((size_t)MP_L * 384 * 2);
  unsigned short* WLp = (unsigned short*)alloc(512 * 384 * 2);
  unsigned short* WCp = (unsigned short*)alloc(512 * 256 * 2);
  unsigned short* wLm1 = (unsigned short*)alloc(DIM * DIM * 2);
  unsigned short* wLm2 = (unsigned short*)alloc(DIM * DIM * 2);
  unsigned short* wLm3 = (unsigned short*)alloc(DIM * DIM * 2);
  unsigned short* wCm1 = (unsigned short*)alloc(DIM * DIM * 2);
  unsigned short* wCm2 = (unsigned short*)alloc(DIM * DIM * 2);
  unsigned short* wCm3 = (unsigned short*)alloc(DIM * DIM * 2);
  unsigned short* wV1  = (unsigned short*)alloc(DIM * DIM * 2);
  unsigned short* wV2  = (unsigned short*)alloc(DIM * DIM * 2);
  int* lit_cnt  = (int*)alloc(N_LITS * 4);
  int* cls_cnt  = (int*)alloc(N_CLAUSES * 4);
  int* lit_fill = (int*)alloc(N_LITS * 4);
  int* cls_fill = (int*)alloc(N_CLAUSES * 4);
  int* lit_ptr  = (int*)alloc((N_LITS + 1) * 4);
  int* cls_ptr  = (int*)alloc((N_CLAUSES + 1) * 4);
  int* lit_col  = (int*)alloc(N_CELLS * 4);
  int* cls_col  = (int*)alloc(N_CELLS * 4);
  if (off > ws_size) return;

  // ---- CSR build (redone every launch) ----
  hipMemsetAsync(lit_cnt, 0, (char*)lit_ptr - (char*)lit_cnt, stream);
  count_kernel<<<(N_CELLS + 255) / 256, 256, 0, stream>>>(uidx, lit_cnt, cls_cnt);
  scan_kernel<<<1, 1024, 0, stream>>>(lit_cnt, lit_ptr, N_LITS);
  scan_kernel<<<1, 1024, 0, stream>>>(cls_cnt, cls_ptr, N_CLAUSES);
  scatter_kernel<<<(N_CELLS + 255) / 256, 256, 0, stream>>>(
      uidx, lit_ptr, cls_ptr, lit_fill, cls_fill, lit_col, cls_col);

  // ---- one-time weight conversion / packing / state init ----
  init_state_kernel<<<(N_CLAUSES * DIM + 255) / 256, 256, 0, stream>>>(
      L_init_w, L_init_b, C_init_w, C_init_b, Lh, Lc, Ch, Cc);
  pack_gates_kernel<256><<<(512 * 384 + 255) / 256, 256, 0, stream>>>(
      Lu_wih, Lu_whh, Lu_bih, Lu_bhh, WLp, bL);
  pack_gates_kernel<128><<<(512 * 256 + 255) / 256, 256, 0, stream>>>(
      Cu_wih, Cu_whh, Cu_bih, Cu_bhh, WCp, bC);
  dim3 cgrid(DIM * DIM / 256, 8);
  cvt8_kernel<<<cgrid, 256, 0, stream>>>(
      Lmsg_w1, Lmsg_w2, Lmsg_w3, Cmsg_w1, Cmsg_w2, Cmsg_w3, Lvote_w1, Lvote_w2,
      wLm1, wLm2, wLm3, wCm1, wCm2, wCm3, wV1, wV2);

  // ---- prologue: T_L = L-MLP(Lh0) ----
  fused_mlp3<<<N_LITS / 64, 256, 0, stream>>>(
      Lh, wLm1, Lmsg_b1, wLm2, Lmsg_b2, wLm3, Lmsg_b3, TL);

  // ---- message-passing rounds: 6 kernels per round ----
  for (int r = 0; r < N_ROUNDS; ++r) {
    gather_cls<<<N_CLAUSES / 4, 256, 0, stream>>>(cls_ptr, cls_col, TL, Ch, XC);
    gemm_lstm<4><<<dim3(4, N_CLAUSES / 128), 256, 0, stream>>>(XC, WCp, bC, Cc, Ch);
    fused_mlp3<<<N_CLAUSES / 64, 256, 0, stream>>>(
        Ch, wCm1, Cmsg_b1, wCm2, Cmsg_b2, wCm3, Cmsg_b3, TC);
    gather_lit<<<MP_L / 4, 256, 0, stream>>>(lit_ptr, lit_col, TC, Lh, XL);
    gemm_lstm<6><<<dim3(4, MP_L / 128), 256, 0, stream>>>(XL, WLp, bL, Lc, Lh);
    fused_mlp3<<<N_LITS / 64, 256, 0, stream>>>(
        Lh, wLm1, Lmsg_b1, wLm2, Lmsg_b2, wLm3, Lmsg_b3, TL);
  }

  // ---- vote + per-problem mean ----
  fused_vote<<<N_LITS / 64, 256, 0, stream>>>(
      Lh, wV1, Lvote_b1, wV2, Lvote_b2, Lvote_w3, Lvote_b3, vote);
  prob_mean_kernel<<<N_PROBS, 256, 0, stream>>>(vote, out);
}

// Round 7
// 1137.661 us; speedup vs baseline: 1.5427x; 1.5427x over previous
//
#include <hip/hip_runtime.h>
#include <cstdint>
#include <cstddef>

#define N_VARS   4000
#define N_LITS   8000
#define N_CLAUSES 16000
#define N_CELLS  48000
#define DIM      128
#define N_ROUNDS 16
#define N_PROBS  8

typedef __bf16 bf16x8 __attribute__((ext_vector_type(8)));
typedef float f32x4 __attribute__((ext_vector_type(4)));

__device__ inline unsigned short f2bf(float x) {
  unsigned int u = __float_as_uint(x);
  u += 0x7fffu + ((u >> 16) & 1u);          // RTNE
  return (unsigned short)(u >> 16);
}
__device__ inline float bflo(unsigned int v) { return __uint_as_float(v << 16); }
__device__ inline float bfhi(unsigned int v) { return __uint_as_float(v & 0xffff0000u); }
__device__ inline unsigned int pack2(float a, float b) {
  return (unsigned int)f2bf(a) | ((unsigned int)f2bf(b) << 16);
}
__device__ inline bf16x8 ld_frag(const unsigned short* p) {
  uint4 u = *reinterpret_cast<const uint4*>(p);
  return __builtin_bit_cast(bf16x8, u);
}
__device__ inline float fast_sigmoid(float x) { return 1.f / (1.f + __expf(-x)); }
__device__ inline float fast_tanh(float x) {
  float t = __expf(-2.f * x);
  return (1.f - t) / (1.f + t);
}

// ===========================================================================
// fused_round<KS, LIT>: one half-round, 32 rows/block, 512 thr = 8 waves.
//  1a: 64 x 8-lane groups: (row = g&31, part = g>>5) sums CSR neighbors
//      j===part (mod 2) of Tsrc into fp32 LDS partials (serial chain halved).
//  1b: combine partials -> bf16 msg; stage hold rows (own + flip) into LDS.
//  2:  gates[32,512] = [msg | h...] @ Wp^T + bP. Wave w owns gate-cols
//      [w*64,(w+1)*64). Wp gate-permuted: np = w*64 + tt*16 + kc*4 + j
//      <-> gate j, dim d = w*16 + kc*4 + tt. Lane (r,kc) of wave w holds
//      i,f,g,o of (row0+rg*16+r, dim d) in acc[rg][tt][0..3]; tt=0..3 are
//      4 contiguous dims -> f32x4 c RMW, uint2 h. Zero-shuffle LSTM.
//  3:  Tout = 3-layer MLP(h_new) from LDS; wave w: rows (w>>2)*16.., tiles
//      (w&3)*2..+2.
// B-frag per ks: ks<4 msg; C: ks4-7 hsA(own); L: ks4-7 hsF(flip), 8-11 hsA.
// Safe vs round4's race: hold read only in 1b staging, h written after a
// barrier following all LDS reads.
// ===========================================================================
template<int KS, bool LIT>
__global__ __launch_bounds__(512, 4) void fused_round(
    const int* __restrict__ ptr, const int* __restrict__ col,
    const unsigned short* __restrict__ Tsrc,
    const unsigned short* hold, unsigned short* hnew,   // may alias (C side)
    float* __restrict__ cst,
    const unsigned short* __restrict__ Wp, const float* __restrict__ bP,
    const unsigned short* __restrict__ Wm1, const float* __restrict__ bm1,
    const unsigned short* __restrict__ Wm2, const float* __restrict__ bm2,
    const unsigned short* __restrict__ Wm3, const float* __restrict__ bm3,
    unsigned short* __restrict__ Tout) {
  constexpr int K = KS * 32;
  __shared__ __align__(16) float pmsg[2][32][132];
  __shared__ __align__(16) unsigned short msg[32][136];
  __shared__ __align__(16) unsigned short hsA[32][136];
  __shared__ __align__(16) unsigned short hsF[32][136];
  __shared__ __align__(16) unsigned short xb[32][136];
  const int tid = threadIdx.x;
  const int w = tid >> 6, l = tid & 63;
  const int r = l & 15, kc = l >> 4;
  const int row0 = blockIdx.x * 32;

  // ---- phase 1a: split gather into fp32 partials ----
  {
    const int g8 = tid >> 3, gl = tid & 7;
    const int grow = g8 & 31, part = g8 >> 5;
    const int row = row0 + grow;
    const int b = ptr[row], e = ptr[row + 1];
    float s[16];
#pragma unroll
    for (int q = 0; q < 16; ++q) s[q] = 0.f;
    int j = b + part;
    int c0 = (j < e) ? col[j] : 0;
    while (j < e) {
      const int jn = j + 2;
      const int c1 = (jn < e) ? col[jn] : 0;
      const unsigned short* src = &Tsrc[(size_t)c0 * 128 + gl * 16];
      const uint4 v0 = *reinterpret_cast<const uint4*>(src);
      const uint4 v1 = *reinterpret_cast<const uint4*>(src + 8);
      s[0]  += bflo(v0.x); s[1]  += bfhi(v0.x);
      s[2]  += bflo(v0.y); s[3]  += bfhi(v0.y);
      s[4]  += bflo(v0.z); s[5]  += bfhi(v0.z);
      s[6]  += bflo(v0.w); s[7]  += bfhi(v0.w);
      s[8]  += bflo(v1.x); s[9]  += bfhi(v1.x);
      s[10] += bflo(v1.y); s[11] += bfhi(v1.y);
      s[12] += bflo(v1.z); s[13] += bfhi(v1.z);
      s[14] += bflo(v1.w); s[15] += bfhi(v1.w);
      j = jn; c0 = c1;
    }
    float* pd = &pmsg[part][grow][gl * 16];
#pragma unroll
    for (int q = 0; q < 4; ++q)
      *reinterpret_cast<f32x4*>(pd + q * 4) = (f32x4){s[q * 4], s[q * 4 + 1], s[q * 4 + 2], s[q * 4 + 3]};
  }
  __syncthreads();

  // ---- phase 1b: combine -> bf16 msg; stage hold rows into LDS ----
  {
    const int crow = tid >> 4, cd = (tid & 15) * 8;
    f32x4 p0 = *reinterpret_cast<const f32x4*>(&pmsg[0][crow][cd]);
    f32x4 p1 = *reinterpret_cast<const f32x4*>(&pmsg[0][crow][cd + 4]);
    f32x4 q0 = *reinterpret_cast<const f32x4*>(&pmsg[1][crow][cd]);
    f32x4 q1 = *reinterpret_cast<const f32x4*>(&pmsg[1][crow][cd + 4]);
    uint4 o;
    o.x = pack2(p0[0] + q0[0], p0[1] + q0[1]);
    o.y = pack2(p0[2] + q0[2], p0[3] + q0[3]);
    o.z = pack2(p1[0] + q1[0], p1[1] + q1[1]);
    o.w = pack2(p1[2] + q1[2], p1[3] + q1[3]);
    *reinterpret_cast<uint4*>(&msg[crow][cd]) = o;
    *reinterpret_cast<uint4*>(&hsA[crow][cd]) =
        *reinterpret_cast<const uint4*>(&hold[(size_t)(row0 + crow) * 128 + cd]);
    if (LIT) {
      const int frow0 = row0 + ((row0 < N_VARS) ? N_VARS : -N_VARS);
      *reinterpret_cast<uint4*>(&hsF[crow][cd]) =
          *reinterpret_cast<const uint4*>(&hold[(size_t)(frow0 + crow) * 128 + cd]);
    }
  }
  __syncthreads();

  // ---- phase 2: gates GEMM ----
  f32x4 acc[2][4];
#pragma unroll
  for (int rg = 0; rg < 2; ++rg)
#pragma unroll
    for (int t = 0; t < 4; ++t) acc[rg][t] = (f32x4){0.f, 0.f, 0.f, 0.f};

#pragma unroll
  for (int ks = 0; ks < KS; ++ks) {
    bf16x8 bfr[2];
#pragma unroll
    for (int rg = 0; rg < 2; ++rg) {
      const int xr = rg * 16 + r;
      if (ks < 4)        bfr[rg] = ld_frag(&msg[xr][ks * 32 + kc * 8]);
      else if (!LIT)     bfr[rg] = ld_frag(&hsA[xr][(ks - 4) * 32 + kc * 8]);
      else if (ks < 8)   bfr[rg] = ld_frag(&hsF[xr][(ks - 4) * 32 + kc * 8]);
      else               bfr[rg] = ld_frag(&hsA[xr][(ks - 8) * 32 + kc * 8]);
    }
#pragma unroll
    for (int tt = 0; tt < 4; ++tt) {
      bf16x8 afr = ld_frag(&Wp[(size_t)(w * 64 + tt * 16 + r) * K + ks * 32 + kc * 8]);
      acc[0][tt] = __builtin_amdgcn_mfma_f32_16x16x32_bf16(afr, bfr[0], acc[0][tt], 0, 0, 0);
      acc[1][tt] = __builtin_amdgcn_mfma_f32_16x16x32_bf16(afr, bfr[1], acc[1][tt], 0, 0, 0);
    }
  }
  __syncthreads();   // all LDS reads of hsA/hsF done before hsA is overwritten

  // ---- LSTM epilogue (zero-shuffle) ----
  {
    const int d0 = w * 16 + kc * 4;
#pragma unroll
    for (int rg = 0; rg < 2; ++rg) {
      const int row = row0 + rg * 16 + r;
      const size_t cb = (size_t)row * 128 + d0;
      f32x4 cv = *reinterpret_cast<const f32x4*>(&cst[cb]);
      f32x4 cn4;
      unsigned int hp[2];
#pragma unroll
      for (int tt = 0; tt < 4; ++tt) {
        const float4 bb = *reinterpret_cast<const float4*>(&bP[w * 64 + tt * 16 + kc * 4]);
        float ig = acc[rg][tt][0] + bb.x;
        float fg = acc[rg][tt][1] + bb.y;
        float gg = acc[rg][tt][2] + bb.z;
        float og = acc[rg][tt][3] + bb.w;
        float cn = fast_sigmoid(fg) * cv[tt] + fast_sigmoid(ig) * fast_tanh(gg);
        float hv = fast_sigmoid(og) * fast_tanh(cn);
        cn4[tt] = cn;
        if (tt & 1) hp[tt >> 1] |= (unsigned int)f2bf(hv) << 16;
        else        hp[tt >> 1]  = (unsigned int)f2bf(hv);
      }
      *reinterpret_cast<f32x4*>(&cst[cb]) = cn4;
      uint2 hv2 = {hp[0], hp[1]};
      *reinterpret_cast<uint2*>(&hnew[cb]) = hv2;
      *reinterpret_cast<uint2*>(&hsA[rg * 16 + r][d0]) = hv2;
    }
  }
  __syncthreads();

  // ---- phase 3: 3-layer MLP on new h ----
  const int mrg = w >> 2;
  const int t0 = (w & 3) * 2;
  {
    f32x4 a2[2] = {(f32x4){0.f, 0.f, 0.f, 0.f}, (f32x4){0.f, 0.f, 0.f, 0.f}};
#pragma unroll
    for (int ks = 0; ks < 4; ++ks) {
      bf16x8 af = ld_frag(&hsA[mrg * 16 + r][ks * 32 + kc * 8]);
#pragma unroll
      for (int q = 0; q < 2; ++q) {
        bf16x8 bf = ld_frag(&Wm1[(size_t)((t0 + q) * 16 + r) * 128 + ks * 32 + kc * 8]);
        a2[q] = __builtin_amdgcn_mfma_f32_16x16x32_bf16(af, bf, a2[q], 0, 0, 0);
      }
    }
#pragma unroll
    for (int q = 0; q < 2; ++q) {
      float bv = bm1[(t0 + q) * 16 + r];
#pragma unroll
      for (int j = 0; j < 4; ++j)
        xb[mrg * 16 + kc * 4 + j][(t0 + q) * 16 + r] = f2bf(fmaxf(a2[q][j] + bv, 0.f));
    }
  }
  __syncthreads();
  {
    f32x4 a2[2] = {(f32x4){0.f, 0.f, 0.f, 0.f}, (f32x4){0.f, 0.f, 0.f, 0.f}};
#pragma unroll
    for (int ks = 0; ks < 4; ++ks) {
      bf16x8 af = ld_frag(&xb[mrg * 16 + r][ks * 32 + kc * 8]);
#pragma unroll
      for (int q = 0; q < 2; ++q) {
        bf16x8 bf = ld_frag(&Wm2[(size_t)((t0 + q) * 16 + r) * 128 + ks * 32 + kc * 8]);
        a2[q] = __builtin_amdgcn_mfma_f32_16x16x32_bf16(af, bf, a2[q], 0, 0, 0);
      }
    }
#pragma unroll
    for (int q = 0; q < 2; ++q) {
      float bv = bm2[(t0 + q) * 16 + r];
#pragma unroll
      for (int j = 0; j < 4; ++j)
        msg[mrg * 16 + kc * 4 + j][(t0 + q) * 16 + r] = f2bf(fmaxf(a2[q][j] + bv, 0.f));
    }
  }
  __syncthreads();
  {
    f32x4 a2[2] = {(f32x4){0.f, 0.f, 0.f, 0.f}, (f32x4){0.f, 0.f, 0.f, 0.f}};
#pragma unroll
    for (int ks = 0; ks < 4; ++ks) {
      bf16x8 af = ld_frag(&msg[mrg * 16 + r][ks * 32 + kc * 8]);
#pragma unroll
      for (int q = 0; q < 2; ++q) {
        bf16x8 bf = ld_frag(&Wm3[(size_t)((t0 + q) * 16 + r) * 128 + ks * 32 + kc * 8]);
        a2[q] = __builtin_amdgcn_mfma_f32_16x16x32_bf16(af, bf, a2[q], 0, 0, 0);
      }
    }
#pragma unroll
    for (int q = 0; q < 2; ++q) {
      float bv = bm3[(t0 + q) * 16 + r];
#pragma unroll
      for (int j = 0; j < 4; ++j)
        Tout[(size_t)(row0 + mrg * 16 + kc * 4 + j) * 128 + (t0 + q) * 16 + r] =
            f2bf(a2[q][j] + bv);
    }
  }
}

// ---------------------------------------------------------------------------
// Prologue 3-layer MLP: 256 thr = 4 waves, 64 rows/block, wave-private.
// ---------------------------------------------------------------------------
__global__ __launch_bounds__(256) void fused_mlp3(
    const unsigned short* __restrict__ A,
    const unsigned short* __restrict__ W1, const float* __restrict__ b1,
    const unsigned short* __restrict__ W2, const float* __restrict__ b2,
    const unsigned short* __restrict__ W3, const float* __restrict__ b3,
    unsigned short* __restrict__ out) {
  __shared__ __align__(16) unsigned short xbuf[2][4][16][136];
  const int w = threadIdx.x >> 6, l = threadIdx.x & 63;
  const int r = l & 15, kc = l >> 4;
  const int row0 = blockIdx.x * 64 + w * 16;

  f32x4 acc[8];
#pragma unroll
  for (int t = 0; t < 8; ++t) acc[t] = (f32x4){0.f, 0.f, 0.f, 0.f};
#pragma unroll
  for (int ks = 0; ks < 4; ++ks) {
    bf16x8 a = ld_frag(&A[(size_t)(row0 + r) * 128 + ks * 32 + kc * 8]);
#pragma unroll
    for (int t = 0; t < 8; ++t) {
      bf16x8 b = ld_frag(&W1[(size_t)(t * 16 + r) * 128 + ks * 32 + kc * 8]);
      acc[t] = __builtin_amdgcn_mfma_f32_16x16x32_bf16(a, b, acc[t], 0, 0, 0);
    }
  }
#pragma unroll
  for (int t = 0; t < 8; ++t) {
    float bv = b1[t * 16 + r];
#pragma unroll
    for (int j = 0; j < 4; ++j)
      xbuf[0][w][kc * 4 + j][t * 16 + r] = f2bf(fmaxf(acc[t][j] + bv, 0.f));
  }
#pragma unroll
  for (int t = 0; t < 8; ++t) acc[t] = (f32x4){0.f, 0.f, 0.f, 0.f};
#pragma unroll
  for (int ks = 0; ks < 4; ++ks) {
    bf16x8 a = ld_frag(&xbuf[0][w][r][ks * 32 + kc * 8]);
#pragma unroll
    for (int t = 0; t < 8; ++t) {
      bf16x8 b = ld_frag(&W2[(size_t)(t * 16 + r) * 128 + ks * 32 + kc * 8]);
      acc[t] = __builtin_amdgcn_mfma_f32_16x16x32_bf16(a, b, acc[t], 0, 0, 0);
    }
  }
#pragma unroll
  for (int t = 0; t < 8; ++t) {
    float bv = b2[t * 16 + r];
#pragma unroll
    for (int j = 0; j < 4; ++j)
      xbuf[1][w][kc * 4 + j][t * 16 + r] = f2bf(fmaxf(acc[t][j] + bv, 0.f));
  }
#pragma unroll
  for (int t = 0; t < 8; ++t) acc[t] = (f32x4){0.f, 0.f, 0.f, 0.f};
#pragma unroll
  for (int ks = 0; ks < 4; ++ks) {
    bf16x8 a = ld_frag(&xbuf[1][w][r][ks * 32 + kc * 8]);
#pragma unroll
    for (int t = 0; t < 8; ++t) {
      bf16x8 b = ld_frag(&W3[(size_t)(t * 16 + r) * 128 + ks * 32 + kc * 8]);
      acc[t] = __builtin_amdgcn_mfma_f32_16x16x32_bf16(a, b, acc[t], 0, 0, 0);
    }
  }
#pragma unroll
  for (int t = 0; t < 8; ++t) {
    float bv = b3[t * 16 + r];
#pragma unroll
    for (int j = 0; j < 4; ++j)
      out[(size_t)(row0 + kc * 4 + j) * 128 + t * 16 + r] = f2bf(acc[t][j] + bv);
  }
}

// ---------------------------------------------------------------------------
// Fused vote: relu(relu(A@W1^T+b1)@W2^T+b2) . w3 + b3 -> vote[M] (fp32)
// ---------------------------------------------------------------------------
__global__ __launch_bounds__(256) void fused_vote(
    const unsigned short* __restrict__ A,
    const unsigned short* __restrict__ W1, const float* __restrict__ b1,
    const unsigned short* __restrict__ W2, const float* __restrict__ b2,
    const float* __restrict__ w3, const float* __restrict__ b3,
    float* __restrict__ vote) {
  __shared__ __align__(16) unsigned short xbuf[4][16][136];
  const int w = threadIdx.x >> 6, l = threadIdx.x & 63;
  const int r = l & 15, kc = l >> 4;
  const int row0 = blockIdx.x * 64 + w * 16;

  f32x4 acc[8];
#pragma unroll
  for (int t = 0; t < 8; ++t) acc[t] = (f32x4){0.f, 0.f, 0.f, 0.f};
#pragma unroll
  for (int ks = 0; ks < 4; ++ks) {
    bf16x8 a = ld_frag(&A[(size_t)(row0 + r) * 128 + ks * 32 + kc * 8]);
#pragma unroll
    for (int t = 0; t < 8; ++t) {
      bf16x8 b = ld_frag(&W1[(size_t)(t * 16 + r) * 128 + ks * 32 + kc * 8]);
      acc[t] = __builtin_amdgcn_mfma_f32_16x16x32_bf16(a, b, acc[t], 0, 0, 0);
    }
  }
#pragma unroll
  for (int t = 0; t < 8; ++t) {
    float bv = b1[t * 16 + r];
#pragma unroll
    for (int j = 0; j < 4; ++j)
      xbuf[w][kc * 4 + j][t * 16 + r] = f2bf(fmaxf(acc[t][j] + bv, 0.f));
  }
#pragma unroll
  for (int t = 0; t < 8; ++t) acc[t] = (f32x4){0.f, 0.f, 0.f, 0.f};
#pragma unroll
  for (int ks = 0; ks < 4; ++ks) {
    bf16x8 a = ld_frag(&xbuf[w][r][ks * 32 + kc * 8]);
#pragma unroll
    for (int t = 0; t < 8; ++t) {
      bf16x8 b = ld_frag(&W2[(size_t)(t * 16 + r) * 128 + ks * 32 + kc * 8]);
      acc[t] = __builtin_amdgcn_mfma_f32_16x16x32_bf16(a, b, acc[t], 0, 0, 0);
    }
  }
  float vs[4] = {0.f, 0.f, 0.f, 0.f};
#pragma unroll
  for (int t = 0; t < 8; ++t) {
    float bv = b2[t * 16 + r], wv = w3[t * 16 + r];
#pragma unroll
    for (int j = 0; j < 4; ++j)
      vs[j] += fmaxf(acc[t][j] + bv, 0.f) * wv;
  }
#pragma unroll
  for (int off = 1; off < 16; off <<= 1) {
#pragma unroll
    for (int j = 0; j < 4; ++j) vs[j] += __shfl_xor(vs[j], off, 16);
  }
  if (r == 0) {
#pragma unroll
    for (int j = 0; j < 4; ++j) vote[row0 + kc * 4 + j] = vs[j] + b3[0];
  }
}

// ---------------------------------------------------------------------------
// One-time prep.
// ---------------------------------------------------------------------------
__global__ void init_state_kernel(const float* __restrict__ Lw, const float* __restrict__ Lb,
                                  const float* __restrict__ Cw, const float* __restrict__ Cb,
                                  unsigned short* __restrict__ Lh, float* __restrict__ Lc,
                                  unsigned short* __restrict__ Ch, float* __restrict__ Cc) {
  int idx = blockIdx.x * 256 + threadIdx.x;
  if (idx >= N_CLAUSES * DIM) return;
  int d = idx & 127;
  Ch[idx] = f2bf(Cw[d] + Cb[d]);
  Cc[idx] = 0.f;
  if (idx < N_LITS * DIM) {
    Lh[idx] = f2bf(Lw[d] + Lb[d]);
    Lc[idx] = 0.f;
  }
}

__global__ void cvt8_kernel(const float* s0, const float* s1, const float* s2, const float* s3,
                            const float* s4, const float* s5, const float* s6, const float* s7,
                            unsigned short* d0, unsigned short* d1, unsigned short* d2,
                            unsigned short* d3, unsigned short* d4, unsigned short* d5,
                            unsigned short* d6, unsigned short* d7) {
  int i = blockIdx.x * 256 + threadIdx.x;
  const float* s; unsigned short* d;
  switch (blockIdx.y) {
    case 0: s = s0; d = d0; break;
    case 1: s = s1; d = d1; break;
    case 2: s = s2; d = d2; break;
    case 3: s = s3; d = d3; break;
    case 4: s = s4; d = d4; break;
    case 5: s = s5; d = d5; break;
    case 6: s = s6; d = d6; break;
    default: s = s7; d = d7; break;
  }
  d[i] = f2bf(s[i]);
}

// Gate-permuted W pack for 64-col waves (see fused_round comment).
// np -> orig: gate = np&3, d = (np>>6)*16 + ((np>>2)&3)*4 + ((np>>4)&3).
template<int KIH>
__global__ void pack_gates_kernel(const float* __restrict__ wih, const float* __restrict__ whh,
                                  const float* __restrict__ bih, const float* __restrict__ bhh,
                                  unsigned short* __restrict__ Wp, float* __restrict__ bP) {
  constexpr int K = KIH + 128;
  int idx = blockIdx.x * 256 + threadIdx.x;
  if (idx >= 512 * K) return;
  int np = idx / K, k = idx % K;
  int gt = np & 3;
  int d = ((np >> 6) << 4) + (((np >> 2) & 3) << 2) + ((np >> 4) & 3);
  int orig = gt * 128 + d;
  float v = (k < KIH) ? wih[(size_t)orig * KIH + k] : whh[(size_t)orig * 128 + (k - KIH)];
  Wp[idx] = f2bf(v);
  if (k == 0) bP[np] = bih[orig] + bhh[orig];
}

// ---------------------------------------------------------------------------
// CSR build.
// ---------------------------------------------------------------------------
__global__ void count_kernel(const int* __restrict__ uidx,
                             int* __restrict__ lit_cnt, int* __restrict__ cls_cnt) {
  int i = blockIdx.x * 256 + threadIdx.x;
  if (i < N_CELLS) {
    atomicAdd(&lit_cnt[uidx[2 * i]], 1);
    atomicAdd(&cls_cnt[uidx[2 * i + 1]], 1);
  }
}

__global__ void scan_kernel(const int* __restrict__ cnt, int* __restrict__ ptr, int n) {
  __shared__ int part[1024];
  __shared__ int total;
  int t = threadIdx.x;
  int chunk = (n + 1023) >> 10;
  int lo = t * chunk, hi = min(lo + chunk, n);
  int s = 0;
  for (int i = lo; i < hi; ++i) s += cnt[i];
  part[t] = s;
  __syncthreads();
  if (t == 0) {
    int acc = 0;
    for (int i = 0; i < 1024; ++i) { int v = part[i]; part[i] = acc; acc += v; }
    total = acc;
  }
  __syncthreads();
  int acc = part[t];
  for (int i = lo; i < hi; ++i) { ptr[i] = acc; acc += cnt[i]; }
  if (t == 0) ptr[n] = total;
}

__global__ void scatter_kernel(const int* __restrict__ uidx,
                               const int* __restrict__ lit_ptr, const int* __restrict__ cls_ptr,
                               int* __restrict__ lit_fill, int* __restrict__ cls_fill,
                               int* __restrict__ lit_col, int* __restrict__ cls_col) {
  int i = blockIdx.x * 256 + threadIdx.x;
  if (i < N_CELLS) {
    int lit = uidx[2 * i], cls = uidx[2 * i + 1];
    int p = atomicAdd(&lit_fill[lit], 1);
    lit_col[lit_ptr[lit] + p] = cls;
    int q = atomicAdd(&cls_fill[cls], 1);
    cls_col[cls_ptr[cls] + q] = lit;
  }
}

__global__ void prob_mean_kernel(const float* __restrict__ vote, float* __restrict__ out) {
  int p = blockIdx.x;
  int t = threadIdx.x;
  float s = 0.f;
  for (int i = t; i < 500; i += 256) s += vote[p * 500 + i] + vote[N_VARS + p * 500 + i];
  __shared__ float red[256];
  red[t] = s;
  __syncthreads();
  for (int off = 128; off > 0; off >>= 1) {
    if (t < off) red[t] += red[t + off];
    __syncthreads();
  }
  if (t == 0) out[p] = red[0] * (1.0f / 1000.0f);
}

// ---------------------------------------------------------------------------
extern "C" void kernel_launch(void* const* d_in, const int* in_sizes, int n_in,
                              void* d_out, int out_size, void* d_ws, size_t ws_size,
                              hipStream_t stream) {
  (void)in_sizes; (void)n_in; (void)out_size;
  const int* uidx = (const int*)d_in[0];
  const float* L_init_w = (const float*)d_in[4];
  const float* L_init_b = (const float*)d_in[5];
  const float* C_init_w = (const float*)d_in[6];
  const float* C_init_b = (const float*)d_in[7];
  const float* Lmsg_w1 = (const float*)d_in[8],  *Lmsg_b1 = (const float*)d_in[9];
  const float* Lmsg_w2 = (const float*)d_in[10], *Lmsg_b2 = (const float*)d_in[11];
  const float* Lmsg_w3 = (const float*)d_in[12], *Lmsg_b3 = (const float*)d_in[13];
  const float* Cmsg_w1 = (const float*)d_in[14], *Cmsg_b1 = (const float*)d_in[15];
  const float* Cmsg_w2 = (const float*)d_in[16], *Cmsg_b2 = (const float*)d_in[17];
  const float* Cmsg_w3 = (const float*)d_in[18], *Cmsg_b3 = (const float*)d_in[19];
  const float* Lvote_w1 = (const float*)d_in[20], *Lvote_b1 = (const float*)d_in[21];
  const float* Lvote_w2 = (const float*)d_in[22], *Lvote_b2 = (const float*)d_in[23];
  const float* Lvote_w3 = (const float*)d_in[24], *Lvote_b3 = (const float*)d_in[25];
  const float* Lu_wih = (const float*)d_in[26], *Lu_whh = (const float*)d_in[27];
  const float* Lu_bih = (const float*)d_in[28], *Lu_bhh = (const float*)d_in[29];
  const float* Cu_wih = (const float*)d_in[30], *Cu_whh = (const float*)d_in[31];
  const float* Cu_bih = (const float*)d_in[32], *Cu_bhh = (const float*)d_in[33];
  float* out = (float*)d_out;

  // ---- workspace carve-up ----
  char* base = (char*)d_ws;
  size_t off = 0;
  auto alloc = [&](size_t bytes) {
    void* p = base + off;
    off = (off + bytes + 255) & ~(size_t)255;
    return p;
  };
  float* Lc   = (float*)alloc((size_t)N_LITS * DIM * 4);
  float* Cc   = (float*)alloc((size_t)N_CLAUSES * DIM * 4);
  float* bL   = (float*)alloc(512 * 4);
  float* bC   = (float*)alloc(512 * 4);
  float* vote = (float*)alloc(N_LITS * 4);
  unsigned short* LhA = (unsigned short*)alloc((size_t)N_LITS * DIM * 2);
  unsigned short* LhB = (unsigned short*)alloc((size_t)N_LITS * DIM * 2);
  unsigned short* Ch  = (unsigned short*)alloc((size_t)N_CLAUSES * DIM * 2);
  unsigned short* TL  = (unsigned short*)alloc((size_t)N_LITS * DIM * 2);
  unsigned short* TC  = (unsigned short*)alloc((size_t)N_CLAUSES * DIM * 2);
  unsigned short* WLp = (unsigned short*)alloc(512 * 384 * 2);
  unsigned short* WCp = (unsigned short*)alloc(512 * 256 * 2);
  unsigned short* wLm1 = (unsigned short*)alloc(DIM * DIM * 2);
  unsigned short* wLm2 = (unsigned short*)alloc(DIM * DIM * 2);
  unsigned short* wLm3 = (unsigned short*)alloc(DIM * DIM * 2);
  unsigned short* wCm1 = (unsigned short*)alloc(DIM * DIM * 2);
  unsigned short* wCm2 = (unsigned short*)alloc(DIM * DIM * 2);
  unsigned short* wCm3 = (unsigned short*)alloc(DIM * DIM * 2);
  unsigned short* wV1  = (unsigned short*)alloc(DIM * DIM * 2);
  unsigned short* wV2  = (unsigned short*)alloc(DIM * DIM * 2);
  int* lit_cnt  = (int*)alloc(N_LITS * 4);
  int* cls_cnt  = (int*)alloc(N_CLAUSES * 4);
  int* lit_fill = (int*)alloc(N_LITS * 4);
  int* cls_fill = (int*)alloc(N_CLAUSES * 4);
  int* lit_ptr  = (int*)alloc((N_LITS + 1) * 4);
  int* cls_ptr  = (int*)alloc((N_CLAUSES + 1) * 4);
  int* lit_col  = (int*)alloc(N_CELLS * 4);
  int* cls_col  = (int*)alloc(N_CELLS * 4);
  if (off > ws_size) return;

  // ---- CSR build (redone every launch) ----
  hipMemsetAsync(lit_cnt, 0, (char*)lit_ptr - (char*)lit_cnt, stream);
  count_kernel<<<(N_CELLS + 255) / 256, 256, 0, stream>>>(uidx, lit_cnt, cls_cnt);
  scan_kernel<<<1, 1024, 0, stream>>>(lit_cnt, lit_ptr, N_LITS);
  scan_kernel<<<1, 1024, 0, stream>>>(cls_cnt, cls_ptr, N_CLAUSES);
  scatter_kernel<<<(N_CELLS + 255) / 256, 256, 0, stream>>>(
      uidx, lit_ptr, cls_ptr, lit_fill, cls_fill, lit_col, cls_col);

  // ---- one-time weight conversion / packing / state init ----
  init_state_kernel<<<(N_CLAUSES * DIM + 255) / 256, 256, 0, stream>>>(
      L_init_w, L_init_b, C_init_w, C_init_b, LhA, Lc, Ch, Cc);
  pack_gates_kernel<256><<<(512 * 384 + 255) / 256, 256, 0, stream>>>(
      Lu_wih, Lu_whh, Lu_bih, Lu_bhh, WLp, bL);
  pack_gates_kernel<128><<<(512 * 256 + 255) / 256, 256, 0, stream>>>(
      Cu_wih, Cu_whh, Cu_bih, Cu_bhh, WCp, bC);
  dim3 cgrid(DIM * DIM / 256, 8);
  cvt8_kernel<<<cgrid, 256, 0, stream>>>(
      Lmsg_w1, Lmsg_w2, Lmsg_w3, Cmsg_w1, Cmsg_w2, Cmsg_w3, Lvote_w1, Lvote_w2,
      wLm1, wLm2, wLm3, wCm1, wCm2, wCm3, wV1, wV2);

  // ---- prologue: T_L = L-MLP(Lh0) ----
  fused_mlp3<<<N_LITS / 64, 256, 0, stream>>>(
      LhA, wLm1, Lmsg_b1, wLm2, Lmsg_b2, wLm3, Lmsg_b3, TL);

  // ---- message-passing rounds: 2 kernels per round ----
  for (int r = 0; r < N_ROUNDS; ++r) {
    fused_round<8, false><<<N_CLAUSES / 32, 512, 0, stream>>>(
        cls_ptr, cls_col, TL, Ch, Ch, Cc, WCp, bC,
        wCm1, Cmsg_b1, wCm2, Cmsg_b2, wCm3, Cmsg_b3, TC);
    const unsigned short* lold = (r & 1) ? LhB : LhA;
    unsigned short* lnew = (r & 1) ? LhA : LhB;
    fused_round<12, true><<<N_LITS / 32, 512, 0, stream>>>(
        lit_ptr, lit_col, TC, lold, lnew, Lc, WLp, bL,
        wLm1, Lmsg_b1, wLm2, Lmsg_b2, wLm3, Lmsg_b3, TL);
  }
  // after 16 rounds (even count), final Lh is in LhA

  // ---- vote + per-problem mean ----
  fused_vote<<<N_LITS / 64, 256, 0, stream>>>(
      LhA, wV1, Lvote_b1, wV2, Lvote_b2, Lvote_w3, Lvote_b3, vote);
  prob_mean_kernel<<<N_PROBS, 256, 0, stream>>>(vote, out);
}

// Round 8
// 715.659 us; speedup vs baseline: 2.4523x; 1.5897x over previous
//
#include <hip/hip_runtime.h>
#include <cstdint>
#include <cstddef>

#define N_VARS   4000
#define N_LITS   8000
#define N_CLAUSES 16000
#define N_CELLS  48000
#define DIM      128
#define N_ROUNDS 16
#define N_PROBS  8

typedef __bf16 bf16x8 __attribute__((ext_vector_type(8)));
typedef float f32x4 __attribute__((ext_vector_type(4)));

__device__ inline unsigned short f2bf(float x) {
  unsigned int u = __float_as_uint(x);
  u += 0x7fffu + ((u >> 16) & 1u);          // RTNE
  return (unsigned short)(u >> 16);
}
__device__ inline float bflo(unsigned int v) { return __uint_as_float(v << 16); }
__device__ inline float bfhi(unsigned int v) { return __uint_as_float(v & 0xffff0000u); }
__device__ inline unsigned int pack2(float a, float b) {
  return (unsigned int)f2bf(a) | ((unsigned int)f2bf(b) << 16);
}
__device__ inline bf16x8 ld_frag(const unsigned short* p) {
  uint4 u = *reinterpret_cast<const uint4*>(p);
  return __builtin_bit_cast(bf16x8, u);
}
__device__ inline float fast_sigmoid(float x) { return 1.f / (1.f + __expf(-x)); }
__device__ inline float fast_tanh(float x) {
  float t = __expf(-2.f * x);
  return (1.f - t) / (1.f + t);
}

// Weight tile layout ("tiled"): a 16(row)x32(k) bf16 MFMA A-fragment tile is
// 1KB contiguous; lane l (= kc*16+r) reads 16B at tile_base + l*16.
// gates Wp: tile id = (w*KS + ks)*4 + tt   (w: wave col-slice, tt: col tile)
// mlp  Wm:  tile id = tt*4 + ks

// ===========================================================================
// fused_round<KS, LIT>: one half-round, 32 rows/block, 512 thr = 8 waves.
//  1a: 64 x 8-lane groups, (row, part): part p sums CSR neighbors j==p (mod 2)
//      of Tsrc in fp32 regs. Part 1 writes its partial to msg as bf16.
//  1b: part 0 adds partner partial from msg, writes final msg; part-1 threads
//      stage hold rows (own + flip) into LDS meanwhile.
//  2:  gates[32,512] = [msg | h...] @ Wp^T + bP; wave w owns gate-cols
//      [w*64,(w+1)*64); tiled Wp loads are 1KB coalesced bursts. Lane (r,kc)
//      holds i,f,g,o of (row0+rg*16+r, dim d=w*16+kc*4+tt) in acc[rg][tt].
//      Zero-shuffle LSTM; c fp32 RMW, h bf16.
//  3:  Tout = 3-layer MLP(h_new); wave w: rows (w>>2)*16.., col tiles (w&3)*2.
// ===========================================================================
template<int KS, bool LIT>
__global__ __launch_bounds__(512, 4) void fused_round(
    const int* __restrict__ ptr, const int* __restrict__ col,
    const unsigned short* __restrict__ Tsrc,
    const unsigned short* hold, unsigned short* hnew,   // may alias (C side)
    float* __restrict__ cst,
    const unsigned short* __restrict__ Wp, const float* __restrict__ bP,
    const unsigned short* __restrict__ Wm1, const float* __restrict__ bm1,
    const unsigned short* __restrict__ Wm2, const float* __restrict__ bm2,
    const unsigned short* __restrict__ Wm3, const float* __restrict__ bm3,
    unsigned short* __restrict__ Tout) {
  __shared__ __align__(16) unsigned short msg[32][136];
  __shared__ __align__(16) unsigned short hsA[32][136];
  __shared__ __align__(16) unsigned short hsF[LIT ? 32 : 1][136];
  __shared__ __align__(16) unsigned short xb[32][136];
  const int tid = threadIdx.x;
  const int w = tid >> 6, l = tid & 63;
  const int r = l & 15, kc = l >> 4;
  const int row0 = blockIdx.x * 32;
  const int flipoff = LIT ? ((row0 < N_VARS) ? N_VARS : -N_VARS) : 0;

  // ---- phase 1a: split gather, fp32 in regs ----
  float s[16];
  {
    const int g8 = tid >> 3, gl = tid & 7;
    const int grow = g8 & 31, part = g8 >> 5;
    const int row = row0 + grow;
    const int b = ptr[row], e = ptr[row + 1];
#pragma unroll
    for (int q = 0; q < 16; ++q) s[q] = 0.f;
    int j = b + part;
    int c0 = (j < e) ? col[j] : 0;
    while (j < e) {
      const int jn = j + 2;
      const int c1 = (jn < e) ? col[jn] : 0;
      const unsigned short* src = &Tsrc[(size_t)c0 * 128 + gl * 16];
      const uint4 v0 = *reinterpret_cast<const uint4*>(src);
      const uint4 v1 = *reinterpret_cast<const uint4*>(src + 8);
      s[0]  += bflo(v0.x); s[1]  += bfhi(v0.x);
      s[2]  += bflo(v0.y); s[3]  += bfhi(v0.y);
      s[4]  += bflo(v0.z); s[5]  += bfhi(v0.z);
      s[6]  += bflo(v0.w); s[7]  += bfhi(v0.w);
      s[8]  += bflo(v1.x); s[9]  += bfhi(v1.x);
      s[10] += bflo(v1.y); s[11] += bfhi(v1.y);
      s[12] += bflo(v1.z); s[13] += bfhi(v1.z);
      s[14] += bflo(v1.w); s[15] += bfhi(v1.w);
      j = jn; c0 = c1;
    }
    if (part == 1) {   // write bf16 partial
      uint4 o0, o1;
      o0.x = pack2(s[0], s[1]);  o0.y = pack2(s[2], s[3]);
      o0.z = pack2(s[4], s[5]);  o0.w = pack2(s[6], s[7]);
      o1.x = pack2(s[8], s[9]);  o1.y = pack2(s[10], s[11]);
      o1.z = pack2(s[12], s[13]); o1.w = pack2(s[14], s[15]);
      *reinterpret_cast<uint4*>(&msg[grow][gl * 16]) = o0;
      *reinterpret_cast<uint4*>(&msg[grow][gl * 16 + 8]) = o1;
    }
  }
  __syncthreads();

  // ---- phase 1b: part 0 combines; part-1 threads stage hold rows ----
  {
    const int g8 = tid >> 3, gl = tid & 7;
    const int grow = g8 & 31, part = g8 >> 5;
    if (part == 0) {
      const uint4 m0 = *reinterpret_cast<const uint4*>(&msg[grow][gl * 16]);
      const uint4 m1 = *reinterpret_cast<const uint4*>(&msg[grow][gl * 16 + 8]);
      s[0]  += bflo(m0.x); s[1]  += bfhi(m0.x);
      s[2]  += bflo(m0.y); s[3]  += bfhi(m0.y);
      s[4]  += bflo(m0.z); s[5]  += bfhi(m0.z);
      s[6]  += bflo(m0.w); s[7]  += bfhi(m0.w);
      s[8]  += bflo(m1.x); s[9]  += bfhi(m1.x);
      s[10] += bflo(m1.y); s[11] += bfhi(m1.y);
      s[12] += bflo(m1.z); s[13] += bfhi(m1.z);
      s[14] += bflo(m1.w); s[15] += bfhi(m1.w);
      uint4 o0, o1;
      o0.x = pack2(s[0], s[1]);  o0.y = pack2(s[2], s[3]);
      o0.z = pack2(s[4], s[5]);  o0.w = pack2(s[6], s[7]);
      o1.x = pack2(s[8], s[9]);  o1.y = pack2(s[10], s[11]);
      o1.z = pack2(s[12], s[13]); o1.w = pack2(s[14], s[15]);
      *reinterpret_cast<uint4*>(&msg[grow][gl * 16]) = o0;
      *reinterpret_cast<uint4*>(&msg[grow][gl * 16 + 8]) = o1;
    } else {
      const int sidx = tid - 256;            // 0..255
#pragma unroll
      for (int q = 0; q < 2; ++q) {
        const int n = sidx + q * 256;        // 0..511 -> 32 rows x 16 uint4
        const int rw = n >> 4, c8 = (n & 15) * 8;
        *reinterpret_cast<uint4*>(&hsA[rw][c8]) =
            *reinterpret_cast<const uint4*>(&hold[(size_t)(row0 + rw) * 128 + c8]);
        if (LIT)
          *reinterpret_cast<uint4*>(&hsF[rw][c8]) =
              *reinterpret_cast<const uint4*>(&hold[(size_t)(row0 + flipoff + rw) * 128 + c8]);
      }
    }
  }
  __syncthreads();

  // ---- phase 2: gates GEMM (tiled W, 1KB bursts) ----
  f32x4 acc[2][4];
#pragma unroll
  for (int rg = 0; rg < 2; ++rg)
#pragma unroll
    for (int t = 0; t < 4; ++t) acc[rg][t] = (f32x4){0.f, 0.f, 0.f, 0.f};

#pragma unroll
  for (int ks = 0; ks < KS; ++ks) {
    bf16x8 bfr[2];
#pragma unroll
    for (int rg = 0; rg < 2; ++rg) {
      const int xr = rg * 16 + r;
      if (ks < 4)        bfr[rg] = ld_frag(&msg[xr][ks * 32 + kc * 8]);
      else if (!LIT)     bfr[rg] = ld_frag(&hsA[xr][(ks - 4) * 32 + kc * 8]);
      else if (ks < 8)   bfr[rg] = ld_frag(&hsF[xr][(ks - 4) * 32 + kc * 8]);
      else               bfr[rg] = ld_frag(&hsA[xr][(ks - 8) * 32 + kc * 8]);
    }
#pragma unroll
    for (int tt = 0; tt < 4; ++tt) {
      bf16x8 afr = ld_frag(&Wp[(size_t)(((w * KS + ks) * 4 + tt) * 64 + l) * 8]);
      acc[0][tt] = __builtin_amdgcn_mfma_f32_16x16x32_bf16(afr, bfr[0], acc[0][tt], 0, 0, 0);
      acc[1][tt] = __builtin_amdgcn_mfma_f32_16x16x32_bf16(afr, bfr[1], acc[1][tt], 0, 0, 0);
    }
  }
  __syncthreads();   // all LDS reads done before hsA is overwritten

  // ---- LSTM epilogue (zero-shuffle) ----
  {
    const int d0 = w * 16 + kc * 4;
#pragma unroll
    for (int rg = 0; rg < 2; ++rg) {
      const int row = row0 + rg * 16 + r;
      const size_t cb = (size_t)row * 128 + d0;
      f32x4 cv = *reinterpret_cast<const f32x4*>(&cst[cb]);
      f32x4 cn4;
      unsigned int hp[2];
#pragma unroll
      for (int tt = 0; tt < 4; ++tt) {
        const float4 bb = *reinterpret_cast<const float4*>(&bP[w * 64 + tt * 16 + kc * 4]);
        float ig = acc[rg][tt][0] + bb.x;
        float fg = acc[rg][tt][1] + bb.y;
        float gg = acc[rg][tt][2] + bb.z;
        float og = acc[rg][tt][3] + bb.w;
        float cn = fast_sigmoid(fg) * cv[tt] + fast_sigmoid(ig) * fast_tanh(gg);
        float hv = fast_sigmoid(og) * fast_tanh(cn);
        cn4[tt] = cn;
        if (tt & 1) hp[tt >> 1] |= (unsigned int)f2bf(hv) << 16;
        else        hp[tt >> 1]  = (unsigned int)f2bf(hv);
      }
      *reinterpret_cast<f32x4*>(&cst[cb]) = cn4;
      uint2 hv2 = {hp[0], hp[1]};
      *reinterpret_cast<uint2*>(&hnew[cb]) = hv2;
      *reinterpret_cast<uint2*>(&hsA[rg * 16 + r][d0]) = hv2;
    }
  }
  __syncthreads();

  // ---- phase 3: 3-layer MLP on new h ----
  const int mrg = w >> 2;
  const int t0 = (w & 3) * 2;
  {
    f32x4 a2[2] = {(f32x4){0.f, 0.f, 0.f, 0.f}, (f32x4){0.f, 0.f, 0.f, 0.f}};
#pragma unroll
    for (int ks = 0; ks < 4; ++ks) {
      bf16x8 af = ld_frag(&hsA[mrg * 16 + r][ks * 32 + kc * 8]);
#pragma unroll
      for (int q = 0; q < 2; ++q) {
        bf16x8 bf = ld_frag(&Wm1[(size_t)(((t0 + q) * 4 + ks) * 64 + l) * 8]);
        a2[q] = __builtin_amdgcn_mfma_f32_16x16x32_bf16(af, bf, a2[q], 0, 0, 0);
      }
    }
#pragma unroll
    for (int q = 0; q < 2; ++q) {
      float bv = bm1[(t0 + q) * 16 + r];
#pragma unroll
      for (int j = 0; j < 4; ++j)
        xb[mrg * 16 + kc * 4 + j][(t0 + q) * 16 + r] = f2bf(fmaxf(a2[q][j] + bv, 0.f));
    }
  }
  __syncthreads();
  {
    f32x4 a2[2] = {(f32x4){0.f, 0.f, 0.f, 0.f}, (f32x4){0.f, 0.f, 0.f, 0.f}};
#pragma unroll
    for (int ks = 0; ks < 4; ++ks) {
      bf16x8 af = ld_frag(&xb[mrg * 16 + r][ks * 32 + kc * 8]);
#pragma unroll
      for (int q = 0; q < 2; ++q) {
        bf16x8 bf = ld_frag(&Wm2[(size_t)(((t0 + q) * 4 + ks) * 64 + l) * 8]);
        a2[q] = __builtin_amdgcn_mfma_f32_16x16x32_bf16(af, bf, a2[q], 0, 0, 0);
      }
    }
#pragma unroll
    for (int q = 0; q < 2; ++q) {
      float bv = bm2[(t0 + q) * 16 + r];
#pragma unroll
      for (int j = 0; j < 4; ++j)
        msg[mrg * 16 + kc * 4 + j][(t0 + q) * 16 + r] = f2bf(fmaxf(a2[q][j] + bv, 0.f));
    }
  }
  __syncthreads();
  {
    f32x4 a2[2] = {(f32x4){0.f, 0.f, 0.f, 0.f}, (f32x4){0.f, 0.f, 0.f, 0.f}};
#pragma unroll
    for (int ks = 0; ks < 4; ++ks) {
      bf16x8 af = ld_frag(&msg[mrg * 16 + r][ks * 32 + kc * 8]);
#pragma unroll
      for (int q = 0; q < 2; ++q) {
        bf16x8 bf = ld_frag(&Wm3[(size_t)(((t0 + q) * 4 + ks) * 64 + l) * 8]);
        a2[q] = __builtin_amdgcn_mfma_f32_16x16x32_bf16(af, bf, a2[q], 0, 0, 0);
      }
    }
#pragma unroll
    for (int q = 0; q < 2; ++q) {
      float bv = bm3[(t0 + q) * 16 + r];
#pragma unroll
      for (int j = 0; j < 4; ++j)
        Tout[(size_t)(row0 + mrg * 16 + kc * 4 + j) * 128 + (t0 + q) * 16 + r] =
            f2bf(a2[q][j] + bv);
    }
  }
}

// ---------------------------------------------------------------------------
// Prologue 3-layer MLP (tiled weights): 256 thr = 4 waves, 64 rows/block.
// ---------------------------------------------------------------------------
__global__ __launch_bounds__(256) void fused_mlp3(
    const unsigned short* __restrict__ A,
    const unsigned short* __restrict__ W1, const float* __restrict__ b1,
    const unsigned short* __restrict__ W2, const float* __restrict__ b2,
    const unsigned short* __restrict__ W3, const float* __restrict__ b3,
    unsigned short* __restrict__ out) {
  __shared__ __align__(16) unsigned short xbuf[2][4][16][136];
  const int w = threadIdx.x >> 6, l = threadIdx.x & 63;
  const int r = l & 15, kc = l >> 4;
  const int row0 = blockIdx.x * 64 + w * 16;

  f32x4 acc[8];
#pragma unroll
  for (int t = 0; t < 8; ++t) acc[t] = (f32x4){0.f, 0.f, 0.f, 0.f};
#pragma unroll
  for (int ks = 0; ks < 4; ++ks) {
    bf16x8 a = ld_frag(&A[(size_t)(row0 + r) * 128 + ks * 32 + kc * 8]);
#pragma unroll
    for (int t = 0; t < 8; ++t) {
      bf16x8 b = ld_frag(&W1[(size_t)((t * 4 + ks) * 64 + l) * 8]);
      acc[t] = __builtin_amdgcn_mfma_f32_16x16x32_bf16(a, b, acc[t], 0, 0, 0);
    }
  }
#pragma unroll
  for (int t = 0; t < 8; ++t) {
    float bv = b1[t * 16 + r];
#pragma unroll
    for (int j = 0; j < 4; ++j)
      xbuf[0][w][kc * 4 + j][t * 16 + r] = f2bf(fmaxf(acc[t][j] + bv, 0.f));
  }
#pragma unroll
  for (int t = 0; t < 8; ++t) acc[t] = (f32x4){0.f, 0.f, 0.f, 0.f};
#pragma unroll
  for (int ks = 0; ks < 4; ++ks) {
    bf16x8 a = ld_frag(&xbuf[0][w][r][ks * 32 + kc * 8]);
#pragma unroll
    for (int t = 0; t < 8; ++t) {
      bf16x8 b = ld_frag(&W2[(size_t)((t * 4 + ks) * 64 + l) * 8]);
      acc[t] = __builtin_amdgcn_mfma_f32_16x16x32_bf16(a, b, acc[t], 0, 0, 0);
    }
  }
#pragma unroll
  for (int t = 0; t < 8; ++t) {
    float bv = b2[t * 16 + r];
#pragma unroll
    for (int j = 0; j < 4; ++j)
      xbuf[1][w][kc * 4 + j][t * 16 + r] = f2bf(fmaxf(acc[t][j] + bv, 0.f));
  }
#pragma unroll
  for (int t = 0; t < 8; ++t) acc[t] = (f32x4){0.f, 0.f, 0.f, 0.f};
#pragma unroll
  for (int ks = 0; ks < 4; ++ks) {
    bf16x8 a = ld_frag(&xbuf[1][w][r][ks * 32 + kc * 8]);
#pragma unroll
    for (int t = 0; t < 8; ++t) {
      bf16x8 b = ld_frag(&W3[(size_t)((t * 4 + ks) * 64 + l) * 8]);
      acc[t] = __builtin_amdgcn_mfma_f32_16x16x32_bf16(a, b, acc[t], 0, 0, 0);
    }
  }
#pragma unroll
  for (int t = 0; t < 8; ++t) {
    float bv = b3[t * 16 + r];
#pragma unroll
    for (int j = 0; j < 4; ++j)
      out[(size_t)(row0 + kc * 4 + j) * 128 + t * 16 + r] = f2bf(acc[t][j] + bv);
  }
}

// ---------------------------------------------------------------------------
// Fused vote (tiled weights): relu(relu(A@W1^T+b1)@W2^T+b2).w3 + b3 -> vote[M]
// ---------------------------------------------------------------------------
__global__ __launch_bounds__(256) void fused_vote(
    const unsigned short* __restrict__ A,
    const unsigned short* __restrict__ W1, const float* __restrict__ b1,
    const unsigned short* __restrict__ W2, const float* __restrict__ b2,
    const float* __restrict__ w3, const float* __restrict__ b3,
    float* __restrict__ vote) {
  __shared__ __align__(16) unsigned short xbuf[4][16][136];
  const int w = threadIdx.x >> 6, l = threadIdx.x & 63;
  const int r = l & 15, kc = l >> 4;
  const int row0 = blockIdx.x * 64 + w * 16;

  f32x4 acc[8];
#pragma unroll
  for (int t = 0; t < 8; ++t) acc[t] = (f32x4){0.f, 0.f, 0.f, 0.f};
#pragma unroll
  for (int ks = 0; ks < 4; ++ks) {
    bf16x8 a = ld_frag(&A[(size_t)(row0 + r) * 128 + ks * 32 + kc * 8]);
#pragma unroll
    for (int t = 0; t < 8; ++t) {
      bf16x8 b = ld_frag(&W1[(size_t)((t * 4 + ks) * 64 + l) * 8]);
      acc[t] = __builtin_amdgcn_mfma_f32_16x16x32_bf16(a, b, acc[t], 0, 0, 0);
    }
  }
#pragma unroll
  for (int t = 0; t < 8; ++t) {
    float bv = b1[t * 16 + r];
#pragma unroll
    for (int j = 0; j < 4; ++j)
      xbuf[w][kc * 4 + j][t * 16 + r] = f2bf(fmaxf(acc[t][j] + bv, 0.f));
  }
#pragma unroll
  for (int t = 0; t < 8; ++t) acc[t] = (f32x4){0.f, 0.f, 0.f, 0.f};
#pragma unroll
  for (int ks = 0; ks < 4; ++ks) {
    bf16x8 a = ld_frag(&xbuf[w][r][ks * 32 + kc * 8]);
#pragma unroll
    for (int t = 0; t < 8; ++t) {
      bf16x8 b = ld_frag(&W2[(size_t)((t * 4 + ks) * 64 + l) * 8]);
      acc[t] = __builtin_amdgcn_mfma_f32_16x16x32_bf16(a, b, acc[t], 0, 0, 0);
    }
  }
  float vs[4] = {0.f, 0.f, 0.f, 0.f};
#pragma unroll
  for (int t = 0; t < 8; ++t) {
    float bv = b2[t * 16 + r], wv = w3[t * 16 + r];
#pragma unroll
    for (int j = 0; j < 4; ++j)
      vs[j] += fmaxf(acc[t][j] + bv, 0.f) * wv;
  }
#pragma unroll
  for (int off = 1; off < 16; off <<= 1) {
#pragma unroll
    for (int j = 0; j < 4; ++j) vs[j] += __shfl_xor(vs[j], off, 16);
  }
  if (r == 0) {
#pragma unroll
    for (int j = 0; j < 4; ++j) vote[row0 + kc * 4 + j] = vs[j] + b3[0];
  }
}

// ---------------------------------------------------------------------------
// One-time prep.
// ---------------------------------------------------------------------------
__global__ void init_state_kernel(const float* __restrict__ Lw, const float* __restrict__ Lb,
                                  const float* __restrict__ Cw, const float* __restrict__ Cb,
                                  unsigned short* __restrict__ Lh, float* __restrict__ Lc,
                                  unsigned short* __restrict__ Ch, float* __restrict__ Cc) {
  int idx = blockIdx.x * 256 + threadIdx.x;
  if (idx >= N_CLAUSES * DIM) return;
  int d = idx & 127;
  Ch[idx] = f2bf(Cw[d] + Cb[d]);
  Cc[idx] = 0.f;
  if (idx < N_LITS * DIM) {
    Lh[idx] = f2bf(Lw[d] + Lb[d]);
    Lc[idx] = 0.f;
  }
}

// 8 fp32 [128,128] matrices -> bf16 tile-packed (tile id = tt*4+ks).
__global__ void pack8_kernel(const float* s0, const float* s1, const float* s2, const float* s3,
                             const float* s4, const float* s5, const float* s6, const float* s7,
                             unsigned short* d0, unsigned short* d1, unsigned short* d2,
                             unsigned short* d3, unsigned short* d4, unsigned short* d5,
                             unsigned short* d6, unsigned short* d7) {
  int i = blockIdx.x * 256 + threadIdx.x;   // [0, 16384)
  const float* s; unsigned short* d;
  switch (blockIdx.y) {
    case 0: s = s0; d = d0; break;
    case 1: s = s1; d = d1; break;
    case 2: s = s2; d = d2; break;
    case 3: s = s3; d = d3; break;
    case 4: s = s4; d = d4; break;
    case 5: s = s5; d = d5; break;
    case 6: s = s6; d = d6; break;
    default: s = s7; d = d7; break;
  }
  int np = i >> 7, k = i & 127;
  int tt = np >> 4, r = np & 15;
  int ks = k >> 5, kcf = (k >> 3) & 3, e = k & 7;
  int dst = (((tt * 4 + ks) * 64) + kcf * 16 + r) * 8 + e;
  d[dst] = f2bf(s[i]);
}

// Gate-permuted + tile-packed LSTM weight pack.
// np = w*64 + tt*16 + kc*4 + j <-> gate j, dim d = w*16 + kc*4 + tt.
// dest tile id = (w*KS + ks)*4 + tt, lane = kcf*16 + r (r = np&15).
template<int KIH>
__global__ void pack_gates_kernel(const float* __restrict__ wih, const float* __restrict__ whh,
                                  const float* __restrict__ bih, const float* __restrict__ bhh,
                                  unsigned short* __restrict__ Wp, float* __restrict__ bP) {
  constexpr int K = KIH + 128;
  constexpr int KS = K / 32;
  int idx = blockIdx.x * 256 + threadIdx.x;
  if (idx >= 512 * K) return;
  int np = idx / K, k = idx % K;
  int gt = np & 3;
  int d = ((np >> 6) << 4) + (((np >> 2) & 3) << 2) + ((np >> 4) & 3);
  int orig = gt * 128 + d;
  float v = (k < KIH) ? wih[(size_t)orig * KIH + k] : whh[(size_t)orig * 128 + (k - KIH)];
  int w = np >> 6, tt = (np >> 4) & 3, r = np & 15;
  int ks = k >> 5, kcf = (k >> 3) & 3, e = k & 7;
  size_t dst = ((size_t)((w * KS + ks) * 4 + tt) * 64 + kcf * 16 + r) * 8 + e;
  Wp[dst] = f2bf(v);
  if (k == 0) bP[np] = bih[orig] + bhh[orig];
}

// ---------------------------------------------------------------------------
// CSR build.
// ---------------------------------------------------------------------------
__global__ void count_kernel(const int* __restrict__ uidx,
                             int* __restrict__ lit_cnt, int* __restrict__ cls_cnt) {
  int i = blockIdx.x * 256 + threadIdx.x;
  if (i < N_CELLS) {
    atomicAdd(&lit_cnt[uidx[2 * i]], 1);
    atomicAdd(&cls_cnt[uidx[2 * i + 1]], 1);
  }
}

__global__ void scan_kernel(const int* __restrict__ cnt, int* __restrict__ ptr, int n) {
  __shared__ int part[1024];
  __shared__ int total;
  int t = threadIdx.x;
  int chunk = (n + 1023) >> 10;
  int lo = t * chunk, hi = min(lo + chunk, n);
  int s = 0;
  for (int i = lo; i < hi; ++i) s += cnt[i];
  part[t] = s;
  __syncthreads();
  if (t == 0) {
    int acc = 0;
    for (int i = 0; i < 1024; ++i) { int v = part[i]; part[i] = acc; acc += v; }
    total = acc;
  }
  __syncthreads();
  int acc = part[t];
  for (int i = lo; i < hi; ++i) { ptr[i] = acc; acc += cnt[i]; }
  if (t == 0) ptr[n] = total;
}

__global__ void scatter_kernel(const int* __restrict__ uidx,
                               const int* __restrict__ lit_ptr, const int* __restrict__ cls_ptr,
                               int* __restrict__ lit_fill, int* __restrict__ cls_fill,
                               int* __restrict__ lit_col, int* __restrict__ cls_col) {
  int i = blockIdx.x * 256 + threadIdx.x;
  if (i < N_CELLS) {
    int lit = uidx[2 * i], cls = uidx[2 * i + 1];
    int p = atomicAdd(&lit_fill[lit], 1);
    lit_col[lit_ptr[lit] + p] = cls;
    int q = atomicAdd(&cls_fill[cls], 1);
    cls_col[cls_ptr[cls] + q] = lit;
  }
}

__global__ void prob_mean_kernel(const float* __restrict__ vote, float* __restrict__ out) {
  int p = blockIdx.x;
  int t = threadIdx.x;
  float s = 0.f;
  for (int i = t; i < 500; i += 256) s += vote[p * 500 + i] + vote[N_VARS + p * 500 + i];
  __shared__ float red[256];
  red[t] = s;
  __syncthreads();
  for (int off = 128; off > 0; off >>= 1) {
    if (t < off) red[t] += red[t + off];
    __syncthreads();
  }
  if (t == 0) out[p] = red[0] * (1.0f / 1000.0f);
}

// ---------------------------------------------------------------------------
extern "C" void kernel_launch(void* const* d_in, const int* in_sizes, int n_in,
                              void* d_out, int out_size, void* d_ws, size_t ws_size,
                              hipStream_t stream) {
  (void)in_sizes; (void)n_in; (void)out_size;
  const int* uidx = (const int*)d_in[0];
  const float* L_init_w = (const float*)d_in[4];
  const float* L_init_b = (const float*)d_in[5];
  const float* C_init_w = (const float*)d_in[6];
  const float* C_init_b = (const float*)d_in[7];
  const float* Lmsg_w1 = (const float*)d_in[8],  *Lmsg_b1 = (const float*)d_in[9];
  const float* Lmsg_w2 = (const float*)d_in[10], *Lmsg_b2 = (const float*)d_in[11];
  const float* Lmsg_w3 = (const float*)d_in[12], *Lmsg_b3 = (const float*)d_in[13];
  const float* Cmsg_w1 = (const float*)d_in[14], *Cmsg_b1 = (const float*)d_in[15];
  const float* Cmsg_w2 = (const float*)d_in[16], *Cmsg_b2 = (const float*)d_in[17];
  const float* Cmsg_w3 = (const float*)d_in[18], *Cmsg_b3 = (const float*)d_in[19];
  const float* Lvote_w1 = (const float*)d_in[20], *Lvote_b1 = (const float*)d_in[21];
  const float* Lvote_w2 = (const float*)d_in[22], *Lvote_b2 = (const float*)d_in[23];
  const float* Lvote_w3 = (const float*)d_in[24], *Lvote_b3 = (const float*)d_in[25];
  const float* Lu_wih = (const float*)d_in[26], *Lu_whh = (const float*)d_in[27];
  const float* Lu_bih = (const float*)d_in[28], *Lu_bhh = (const float*)d_in[29];
  const float* Cu_wih = (const float*)d_in[30], *Cu_whh = (const float*)d_in[31];
  const float* Cu_bih = (const float*)d_in[32], *Cu_bhh = (const float*)d_in[33];
  float* out = (float*)d_out;

  // ---- workspace carve-up ----
  char* base = (char*)d_ws;
  size_t off = 0;
  auto alloc = [&](size_t bytes) {
    void* p = base + off;
    off = (off + bytes + 255) & ~(size_t)255;
    return p;
  };
  float* Lc   = (float*)alloc((size_t)N_LITS * DIM * 4);
  float* Cc   = (float*)alloc((size_t)N_CLAUSES * DIM * 4);
  float* bL   = (float*)alloc(512 * 4);
  float* bC   = (float*)alloc(512 * 4);
  float* vote = (float*)alloc(N_LITS * 4);
  unsigned short* LhA = (unsigned short*)alloc((size_t)N_LITS * DIM * 2);
  unsigned short* LhB = (unsigned short*)alloc((size_t)N_LITS * DIM * 2);
  unsigned short* Ch  = (unsigned short*)alloc((size_t)N_CLAUSES * DIM * 2);
  unsigned short* TL  = (unsigned short*)alloc((size_t)N_LITS * DIM * 2);
  unsigned short* TC  = (unsigned short*)alloc((size_t)N_CLAUSES * DIM * 2);
  unsigned short* WLp = (unsigned short*)alloc(512 * 384 * 2);
  unsigned short* WCp = (unsigned short*)alloc(512 * 256 * 2);
  unsigned short* wLm1 = (unsigned short*)alloc(DIM * DIM * 2);
  unsigned short* wLm2 = (unsigned short*)alloc(DIM * DIM * 2);
  unsigned short* wLm3 = (unsigned short*)alloc(DIM * DIM * 2);
  unsigned short* wCm1 = (unsigned short*)alloc(DIM * DIM * 2);
  unsigned short* wCm2 = (unsigned short*)alloc(DIM * DIM * 2);
  unsigned short* wCm3 = (unsigned short*)alloc(DIM * DIM * 2);
  unsigned short* wV1  = (unsigned short*)alloc(DIM * DIM * 2);
  unsigned short* wV2  = (unsigned short*)alloc(DIM * DIM * 2);
  int* lit_cnt  = (int*)alloc(N_LITS * 4);
  int* cls_cnt  = (int*)alloc(N_CLAUSES * 4);
  int* lit_fill = (int*)alloc(N_LITS * 4);
  int* cls_fill = (int*)alloc(N_CLAUSES * 4);
  int* lit_ptr  = (int*)alloc((N_LITS + 1) * 4);
  int* cls_ptr  = (int*)alloc((N_CLAUSES + 1) * 4);
  int* lit_col  = (int*)alloc(N_CELLS * 4);
  int* cls_col  = (int*)alloc(N_CELLS * 4);
  if (off > ws_size) return;

  // ---- CSR build (redone every launch) ----
  hipMemsetAsync(lit_cnt, 0, (char*)lit_ptr - (char*)lit_cnt, stream);
  count_kernel<<<(N_CELLS + 255) / 256, 256, 0, stream>>>(uidx, lit_cnt, cls_cnt);
  scan_kernel<<<1, 1024, 0, stream>>>(lit_cnt, lit_ptr, N_LITS);
  scan_kernel<<<1, 1024, 0, stream>>>(cls_cnt, cls_ptr, N_CLAUSES);
  scatter_kernel<<<(N_CELLS + 255) / 256, 256, 0, stream>>>(
      uidx, lit_ptr, cls_ptr, lit_fill, cls_fill, lit_col, cls_col);

  // ---- one-time weight conversion / packing / state init ----
  init_state_kernel<<<(N_CLAUSES * DIM + 255) / 256, 256, 0, stream>>>(
      L_init_w, L_init_b, C_init_w, C_init_b, LhA, Lc, Ch, Cc);
  pack_gates_kernel<256><<<(512 * 384 + 255) / 256, 256, 0, stream>>>(
      Lu_wih, Lu_whh, Lu_bih, Lu_bhh, WLp, bL);
  pack_gates_kernel<128><<<(512 * 256 + 255) / 256, 256, 0, stream>>>(
      Cu_wih, Cu_whh, Cu_bih, Cu_bhh, WCp, bC);
  dim3 cgrid(DIM * DIM / 256, 8);
  pack8_kernel<<<cgrid, 256, 0, stream>>>(
      Lmsg_w1, Lmsg_w2, Lmsg_w3, Cmsg_w1, Cmsg_w2, Cmsg_w3, Lvote_w1, Lvote_w2,
      wLm1, wLm2, wLm3, wCm1, wCm2, wCm3, wV1, wV2);

  // ---- prologue: T_L = L-MLP(Lh0) ----
  fused_mlp3<<<N_LITS / 64, 256, 0, stream>>>(
      LhA, wLm1, Lmsg_b1, wLm2, Lmsg_b2, wLm3, Lmsg_b3, TL);

  // ---- message-passing rounds: 2 kernels per round ----
  for (int r = 0; r < N_ROUNDS; ++r) {
    fused_round<8, false><<<N_CLAUSES / 32, 512, 0, stream>>>(
        cls_ptr, cls_col, TL, Ch, Ch, Cc, WCp, bC,
        wCm1, Cmsg_b1, wCm2, Cmsg_b2, wCm3, Cmsg_b3, TC);
    const unsigned short* lold = (r & 1) ? LhB : LhA;
    unsigned short* lnew = (r & 1) ? LhA : LhB;
    fused_round<12, true><<<N_LITS / 32, 512, 0, stream>>>(
        lit_ptr, lit_col, TC, lold, lnew, Lc, WLp, bL,
        wLm1, Lmsg_b1, wLm2, Lmsg_b2, wLm3, Lmsg_b3, TL);
  }
  // after 16 rounds (even count), final Lh is in LhA

  // ---- vote + per-problem mean ----
  fused_vote<<<N_LITS / 64, 256, 0, stream>>>(
      LhA, wV1, Lvote_b1, wV2, Lvote_b2, Lvote_w3, Lvote_b3, vote);
  prob_mean_kernel<<<N_PROBS, 256, 0, stream>>>(vote, out);
}